// Round 2
// baseline (75.891 us; speedup 1.0000x reference)
//
#include <hip/hip_runtime.h>

#define IMAGE   128
#define NLINES  32
#define NCURVE  64      // N_LINES * N_SEGMENTS
#define NSUB    9       // N_SAMPLES - 1
#define PIX     (IMAGE*IMAGE)

// One block = 256 pixels of one batch image. Curve data staged in LDS.
__global__ __launch_bounds__(256)
void render_kernel(const float* __restrict__ pos,   // (4, 32, 10) fp32
                   const float* __restrict__ rad,   // (4, 32, 1)
                   const float* __restrict__ col,   // (4, 32, 3)
                   const float* __restrict__ bg,    // (4, 3)
                   float* __restrict__ out)         // (4, 3, 128, 128) fp32
{
    __shared__ float4 s_seg[NCURVE*NSUB];   // ax, ay, vx, vy per sub-segment
    __shared__ float  s_rvv[NCURVE*NSUB];   // 1/(v.v + 1e-10)
    __shared__ float  s_isig[NCURVE];       // 1/(radius^2 * 0.05)
    __shared__ float  s_col[NCURVE*3];
    __shared__ float  s_bg[3];

    const int tid  = threadIdx.x;
    const int b    = blockIdx.x >> 6;       // 64 blocks per batch
    const int pblk = blockIdx.x & 63;

    // ---- setup: build 576 polyline sub-segments into LDS ----
    for (int e = tid; e < NCURVE*NSUB; e += 256) {
        const int n    = e / NSUB;          // curve index
        const int j    = e - n*NSUB;        // sub-segment index
        const int line = n >> 1;
        const int seg  = n & 1;
        const float* P = pos + (b*NLINES + line)*10;
        float c0x, c0y, c1x, c1y, c2x, c2y;
        if (seg == 0) {                     // control points p0, p1, p2
            c0x = P[0]; c0y = P[1];
            c1x = P[2]; c1y = P[3];
            c2x = P[4]; c2y = P[5];
        } else {                            // p2, 2*p2 - p3, p4 (reflected middle)
            const float q2x = P[4], q2y = P[5];
            const float q3x = P[6], q3y = P[7];
            c0x = q2x;             c0y = q2y;
            c1x = 2.0f*q2x - q3x;  c1y = 2.0f*q2y - q3y;
            c2x = P[8];            c2y = P[9];
        }
        const float t0 = (float)j     * (1.0f/9.0f);
        const float t1 = (float)(j+1) * (1.0f/9.0f);
        float ax, ay, bx, by;
        {
            const float mt = 1.0f - t0;
            const float w0 = mt*mt, w1 = 2.0f*t0*mt, w2 = t0*t0;
            ax = w0*c0x + w1*c1x + w2*c2x;
            ay = w0*c0y + w1*c1y + w2*c2y;
        }
        {
            const float mt = 1.0f - t1;
            const float w0 = mt*mt, w1 = 2.0f*t1*mt, w2 = t1*t1;
            bx = w0*c0x + w1*c1x + w2*c2x;
            by = w0*c0y + w1*c1y + w2*c2y;
        }
        const float vx = bx - ax, vy = by - ay;
        s_seg[e] = make_float4(ax, ay, vx, vy);
        s_rvv[e] = 1.0f / (vx*vx + vy*vy + 1e-10f);
    }
    if (tid < NCURVE) {
        const float r = rad[b*NLINES + (tid >> 1)];
        s_isig[tid] = 1.0f / (r*r*0.05f);
    }
    if (tid < NCURVE*3) {
        const int n = tid/3, c = tid - n*3;
        s_col[tid] = col[(b*NLINES + (n >> 1))*3 + c];
    }
    if (tid < 3) s_bg[tid] = bg[b*3 + tid];
    __syncthreads();

    // ---- per-pixel main loop ----
    const int p = pblk*256 + tid;                              // pixel id in image
    const float g0 = -1.0f + (float)(p >> 7)  * (2.0f/127.0f); // grid coord 0 (row)
    const float g1 = -1.0f + (float)(p & 127) * (2.0f/127.0f); // grid coord 1 (col)

    float aR = 0.0f, aG = 0.0f, aB = 0.0f, T = 1.0f;
    for (int n = 0; n < NCURVE; ++n) {
        float edt2 = 3.4e38f;
        #pragma unroll
        for (int j = 0; j < NSUB; ++j) {
            const float4 s  = s_seg[n*NSUB + j];
            const float rvv = s_rvv[n*NSUB + j];
            const float d0  = g0 - s.x;
            const float d1  = g1 - s.y;
            const float dt  = d0*s.z + d1*s.w;
            const float tp  = fminf(fmaxf(dt*rvv, 0.0f), 1.0f);
            const float e0  = d0 - tp*s.z;
            const float e1  = d1 - tp*s.w;
            edt2 = fminf(edt2, e0*e0 + e1*e1);
        }
        const float xs = edt2 * s_isig[n];
        const float I  = __expf(-xs*xs);                       // exp(-(edt2/sigma)^2)
        const float wI = I * T;
        aR = fmaf(s_col[n*3+0], wI, aR);
        aG = fmaf(s_col[n*3+1], wI, aG);
        aB = fmaf(s_col[n*3+2], wI, aB);
        T *= (1.0f - I + 1e-10f);                              // transmittance chain
    }
    aR = fmaf(s_bg[0], T, aR);
    aG = fmaf(s_bg[1], T, aG);
    aB = fmaf(s_bg[2], T, aB);

    float* o = out + b*3*PIX + p;
    o[0]     = fminf(fmaxf(aR, 0.0f), 1.0f);
    o[PIX]   = fminf(fmaxf(aG, 0.0f), 1.0f);
    o[2*PIX] = fminf(fmaxf(aB, 0.0f), 1.0f);
}

extern "C" void kernel_launch(void* const* d_in, const int* in_sizes, int n_in,
                              void* d_out, int out_size, void* d_ws, size_t ws_size,
                              hipStream_t stream) {
    const float* pos = (const float*)d_in[0];
    const float* rad = (const float*)d_in[1];
    const float* col = (const float*)d_in[2];
    const float* bg  = (const float*)d_in[3];
    float* out = (float*)d_out;

    // 4 batches * 64 tiles of 256 pixels
    render_kernel<<<dim3(256), dim3(256), 0, stream>>>(pos, rad, col, bg, out);
}

// Round 3
// 74.124 us; speedup vs baseline: 1.0238x; 1.0238x over previous
//
#include <hip/hip_runtime.h>

#define IMAGE   128
#define NLINES  32
#define NCURVE  64      // N_LINES * N_SEGMENTS
#define NSUB    9       // N_SAMPLES - 1
#define PIX     (IMAGE*IMAGE)
#define BS      4
#define NCHUNK  8       // curve chunks per pixel (one per wave)
#define CPC     8       // curves per chunk

// Per-(batch,curve) record in workspace: 64 floats (256 B aligned).
//  [j*4 + 0..3] j=0..8 : ax, ay, vx, vy   (sub-segment)
//  [36 + j]     j=0..8 : 1/(v.v + 1e-10)
//  [48]                : 1/(r^2 * 0.05)
//  [49..51]            : color RGB
#define RECF 64

__global__ __launch_bounds__(256)
void setup_kernel(const float* __restrict__ pos,   // (4, 32, 10)
                  const float* __restrict__ rad,   // (4, 32, 1)
                  const float* __restrict__ col,   // (4, 32, 3)
                  float* __restrict__ tbl)         // (4*64*RECF floats)
{
    const int tid = threadIdx.x;
    for (int e = tid; e < BS*NCURVE*NSUB; e += 256) {
        const int j = e % NSUB;
        const int n = (e / NSUB) & (NCURVE-1);
        const int b = e / (NSUB*NCURVE);
        const int line = n >> 1;
        const int seg  = n & 1;
        const float* P = pos + (b*NLINES + line)*10;
        float c0x, c0y, c1x, c1y, c2x, c2y;
        if (seg == 0) {
            c0x = P[0]; c0y = P[1];
            c1x = P[2]; c1y = P[3];
            c2x = P[4]; c2y = P[5];
        } else {                       // p2, 2*p2 - p3, p4
            const float q2x = P[4], q2y = P[5];
            const float q3x = P[6], q3y = P[7];
            c0x = q2x;             c0y = q2y;
            c1x = 2.0f*q2x - q3x;  c1y = 2.0f*q2y - q3y;
            c2x = P[8];            c2y = P[9];
        }
        const float t0 = (float)j     * (1.0f/9.0f);
        const float t1 = (float)(j+1) * (1.0f/9.0f);
        float ax, ay, bx, by;
        {
            const float mt = 1.0f - t0;
            const float w0 = mt*mt, w1 = 2.0f*t0*mt, w2 = t0*t0;
            ax = w0*c0x + w1*c1x + w2*c2x;
            ay = w0*c0y + w1*c1y + w2*c2y;
        }
        {
            const float mt = 1.0f - t1;
            const float w0 = mt*mt, w1 = 2.0f*t1*mt, w2 = t1*t1;
            bx = w0*c0x + w1*c1x + w2*c2x;
            by = w0*c0y + w1*c1y + w2*c2y;
        }
        const float vx = bx - ax, vy = by - ay;
        float* base = tbl + (b*NCURVE + n)*RECF;
        base[j*4+0] = ax; base[j*4+1] = ay;
        base[j*4+2] = vx; base[j*4+3] = vy;
        base[36+j]  = 1.0f / (vx*vx + vy*vy + 1e-10f);
    }
    // per-curve scalars: 256 records, one per thread
    {
        const int b = tid >> 6, n = tid & (NCURVE-1);
        const int line = n >> 1;
        const float r = rad[b*NLINES + line];
        float* base = tbl + tid*RECF;
        base[48] = 1.0f / (r*r*0.05f);
        base[49] = col[(b*NLINES + line)*3 + 0];
        base[50] = col[(b*NLINES + line)*3 + 1];
        base[51] = col[(b*NLINES + line)*3 + 2];
    }
}

// Block = 512 threads = 8 waves; each wave = one curve-chunk for 64 pixels.
// Curve data addresses are wave-uniform -> scalar (s_load) path.
__global__ __launch_bounds__(512, 8)
void render_kernel(const float* __restrict__ tbl,
                   const float* __restrict__ bg,    // (4, 3)
                   float* __restrict__ out)         // (4, 3, 128, 128)
{
    __shared__ float4 s_part[NCHUNK*64];            // [chunk][pixel] partial (C, T)

    const int tid   = threadIdx.x;
    const int b     = blockIdx.x >> 8;              // 256 tiles per batch
    const int tile  = blockIdx.x & 255;
    const int px    = tid & 63;
    const int chunk = __builtin_amdgcn_readfirstlane(tid >> 6);

    const int p = tile*64 + px;
    const float g0 = -1.0f + (float)(p >> 7)  * (2.0f/127.0f);
    const float g1 = -1.0f + (float)(p & 127) * (2.0f/127.0f);

    float aR = 0.0f, aG = 0.0f, aB = 0.0f, T = 1.0f;
    for (int i = 0; i < CPC; ++i) {
        const int n = chunk*CPC + i;
        const float* __restrict__ base = tbl + (b*NCURVE + n)*RECF;
        float edt2 = 3.4e38f;
        #pragma unroll
        for (int j = 0; j < NSUB; ++j) {
            const float ax = base[j*4+0], ay = base[j*4+1];
            const float vx = base[j*4+2], vy = base[j*4+3];
            const float rvv = base[36+j];
            const float d0  = g0 - ax;
            const float d1  = g1 - ay;
            const float dt  = d0*vx + d1*vy;
            const float tp  = fminf(fmaxf(dt*rvv, 0.0f), 1.0f);
            const float e0  = d0 - tp*vx;
            const float e1  = d1 - tp*vy;
            edt2 = fminf(edt2, e0*e0 + e1*e1);
        }
        const float xs = edt2 * base[48];
        const float I  = __expf(-xs*xs);            // exp(-(edt2/sigma)^2)
        const float wI = I * T;
        aR = fmaf(base[49], wI, aR);
        aG = fmaf(base[50], wI, aG);
        aB = fmaf(base[51], wI, aB);
        T *= (1.0f - I + 1e-10f);
    }
    s_part[chunk*64 + px] = make_float4(aR, aG, aB, T);
    __syncthreads();

    // one wave merges the 8 chunk-partials per pixel, in curve order
    if (tid < 64) {
        float4 acc = s_part[tid];
        float C0 = acc.x, C1 = acc.y, C2 = acc.z, Tt = acc.w;
        #pragma unroll
        for (int c = 1; c < NCHUNK; ++c) {
            const float4 q = s_part[c*64 + tid];
            C0 = fmaf(Tt, q.x, C0);
            C1 = fmaf(Tt, q.y, C1);
            C2 = fmaf(Tt, q.z, C2);
            Tt *= q.w;
        }
        C0 = fmaf(Tt, bg[b*3+0], C0);
        C1 = fmaf(Tt, bg[b*3+1], C1);
        C2 = fmaf(Tt, bg[b*3+2], C2);
        const int po = tile*64 + tid;
        out[(b*3+0)*PIX + po] = fminf(fmaxf(C0, 0.0f), 1.0f);
        out[(b*3+1)*PIX + po] = fminf(fmaxf(C1, 0.0f), 1.0f);
        out[(b*3+2)*PIX + po] = fminf(fmaxf(C2, 0.0f), 1.0f);
    }
}

extern "C" void kernel_launch(void* const* d_in, const int* in_sizes, int n_in,
                              void* d_out, int out_size, void* d_ws, size_t ws_size,
                              hipStream_t stream) {
    const float* pos = (const float*)d_in[0];
    const float* rad = (const float*)d_in[1];
    const float* col = (const float*)d_in[2];
    const float* bg  = (const float*)d_in[3];
    float* out = (float*)d_out;
    float* tbl = (float*)d_ws;                      // 4*64*64 floats = 64 KB

    setup_kernel<<<dim3(1), dim3(256), 0, stream>>>(pos, rad, col, tbl);
    // 4 batches * 256 tiles of 64 pixels, 8 curve-chunks each
    render_kernel<<<dim3(BS*256), dim3(512), 0, stream>>>(tbl, bg, out);
}

// Round 4
// 70.083 us; speedup vs baseline: 1.0829x; 1.0577x over previous
//
#include <hip/hip_runtime.h>

#define IMAGE   128
#define NLINES  32
#define NCURVE  64      // N_LINES * N_SEGMENTS
#define NSUB    9       // N_SAMPLES - 1
#define PIX     (IMAGE*IMAGE)
#define BS      4
#define NCHUNK  8       // curve chunks per pixel (one per wave)
#define CPC     8       // curves per chunk

// Single fused kernel. Block = 512 threads = 8 waves; block covers 64 pixels
// of one batch image; wave w composites curves [8w, 8w+8) for those pixels.
// Curve tables live in LDS; all hot-loop LDS reads are wave-uniform
// (broadcast, conflict-free). Partials merged via LDS at the end.
__global__ __launch_bounds__(512, 8)
void render_kernel(const float* __restrict__ pos,   // (4, 32, 10)
                   const float* __restrict__ rad,   // (4, 32, 1)
                   const float* __restrict__ col,   // (4, 32, 3)
                   const float* __restrict__ bg,    // (4, 3)
                   float* __restrict__ out)         // (4, 3, 128, 128)
{
    __shared__ float4 s_sub4[NCURVE*NSUB];  // ax, ay, vx, vy
    __shared__ float2 s_sub2[NCURVE*NSUB];  // wx = vx/(v.v+eps), wy = vy/(v.v+eps)
    __shared__ float4 s_cur[NCURVE];        // 1/(r^2*0.05), R, G, B
    __shared__ float4 s_part[NCHUNK*64];    // per-chunk partial (C, T)

    const int tid  = threadIdx.x;
    const int b    = blockIdx.x >> 8;       // 256 tile-blocks per batch
    const int tile = blockIdx.x & 255;

    // ---- cooperative setup: 576 sub-segments for this batch ----
    for (int e = tid; e < NCURVE*NSUB; e += 512) {
        const int n    = e / NSUB;          // curve index
        const int j    = e - n*NSUB;        // sub-segment index
        const int line = n >> 1;
        const int seg  = n & 1;
        const float* P = pos + (b*NLINES + line)*10;
        float c0x, c0y, c1x, c1y, c2x, c2y;
        if (seg == 0) {                     // p0, p1, p2
            c0x = P[0]; c0y = P[1];
            c1x = P[2]; c1y = P[3];
            c2x = P[4]; c2y = P[5];
        } else {                            // p2, 2*p2 - p3, p4
            const float q2x = P[4], q2y = P[5];
            const float q3x = P[6], q3y = P[7];
            c0x = q2x;             c0y = q2y;
            c1x = 2.0f*q2x - q3x;  c1y = 2.0f*q2y - q3y;
            c2x = P[8];            c2y = P[9];
        }
        const float t0 = (float)j     * (1.0f/9.0f);
        const float t1 = (float)(j+1) * (1.0f/9.0f);
        float ax, ay, bx, by;
        {
            const float mt = 1.0f - t0;
            const float w0 = mt*mt, w1 = 2.0f*t0*mt, w2 = t0*t0;
            ax = w0*c0x + w1*c1x + w2*c2x;
            ay = w0*c0y + w1*c1y + w2*c2y;
        }
        {
            const float mt = 1.0f - t1;
            const float w0 = mt*mt, w1 = 2.0f*t1*mt, w2 = t1*t1;
            bx = w0*c0x + w1*c1x + w2*c2x;
            by = w0*c0y + w1*c1y + w2*c2y;
        }
        const float vx = bx - ax, vy = by - ay;
        const float rvv = 1.0f / (vx*vx + vy*vy + 1e-10f);
        s_sub4[e] = make_float4(ax, ay, vx, vy);
        s_sub2[e] = make_float2(vx*rvv, vy*rvv);
    }
    if (tid < NCURVE) {
        const int line = tid >> 1;
        const float r  = rad[b*NLINES + line];
        s_cur[tid] = make_float4(1.0f / (r*r*0.05f),
                                 col[(b*NLINES + line)*3 + 0],
                                 col[(b*NLINES + line)*3 + 1],
                                 col[(b*NLINES + line)*3 + 2]);
    }
    __syncthreads();

    // ---- hot loop: 8 curves per wave, 64 pixels per wave ----
    const int px    = tid & 63;
    const int chunk = tid >> 6;             // == wave id, wave-uniform
    const int p     = tile*64 + px;
    const float g0  = -1.0f + (float)(p >> 7)  * (2.0f/127.0f);
    const float g1  = -1.0f + (float)(p & 127) * (2.0f/127.0f);

    float aR = 0.0f, aG = 0.0f, aB = 0.0f, T = 1.0f;
    for (int i = 0; i < CPC; ++i) {
        const int n = chunk*CPC + i;
        float edt2 = 3.4e38f;
        #pragma unroll 3
        for (int j = 0; j < NSUB; ++j) {
            const float4 s = s_sub4[n*NSUB + j];
            const float2 w = s_sub2[n*NSUB + j];
            const float d0 = g0 - s.x;
            const float d1 = g1 - s.y;
            const float tp = fminf(fmaxf(d0*w.x + d1*w.y, 0.0f), 1.0f);
            const float e0 = fmaf(-tp, s.z, d0);
            const float e1 = fmaf(-tp, s.w, d1);
            edt2 = fminf(edt2, fmaf(e0, e0, e1*e1));
        }
        const float4 cu = s_cur[n];
        const float xs  = edt2 * cu.x;
        const float I   = __expf(-xs*xs);   // exp(-(edt2/sigma)^2)
        const float wI  = I * T;
        aR = fmaf(cu.y, wI, aR);
        aG = fmaf(cu.z, wI, aG);
        aB = fmaf(cu.w, wI, aB);
        T *= (1.0f - I + 1e-10f);           // transmittance chain
    }
    s_part[chunk*64 + px] = make_float4(aR, aG, aB, T);
    __syncthreads();

    // ---- merge the 8 chunk-partials per pixel, in curve order ----
    if (tid < 64) {
        float4 acc = s_part[tid];
        float C0 = acc.x, C1 = acc.y, C2 = acc.z, Tt = acc.w;
        #pragma unroll
        for (int c = 1; c < NCHUNK; ++c) {
            const float4 q = s_part[c*64 + tid];
            C0 = fmaf(Tt, q.x, C0);
            C1 = fmaf(Tt, q.y, C1);
            C2 = fmaf(Tt, q.z, C2);
            Tt *= q.w;
        }
        C0 = fmaf(Tt, bg[b*3+0], C0);
        C1 = fmaf(Tt, bg[b*3+1], C1);
        C2 = fmaf(Tt, bg[b*3+2], C2);
        const int po = tile*64 + tid;
        out[(b*3+0)*PIX + po] = fminf(fmaxf(C0, 0.0f), 1.0f);
        out[(b*3+1)*PIX + po] = fminf(fmaxf(C1, 0.0f), 1.0f);
        out[(b*3+2)*PIX + po] = fminf(fmaxf(C2, 0.0f), 1.0f);
    }
}

extern "C" void kernel_launch(void* const* d_in, const int* in_sizes, int n_in,
                              void* d_out, int out_size, void* d_ws, size_t ws_size,
                              hipStream_t stream) {
    const float* pos = (const float*)d_in[0];
    const float* rad = (const float*)d_in[1];
    const float* col = (const float*)d_in[2];
    const float* bg  = (const float*)d_in[3];
    float* out = (float*)d_out;

    // 4 batches * 256 tiles of 64 pixels; 8 curve-chunk waves per block
    render_kernel<<<dim3(BS*256), dim3(512), 0, stream>>>(pos, rad, col, bg, out);
}

// Round 5
// 68.955 us; speedup vs baseline: 1.1006x; 1.0164x over previous
//
#include <hip/hip_runtime.h>

#define IMAGE   128
#define NLINES  32
#define NCURVE  64      // N_LINES * N_SEGMENTS
#define NSUB    9       // N_SAMPLES - 1
#define PIX     (IMAGE*IMAGE)
#define BS      4
#define NCHUNK  8       // curve chunks (one per wave)
#define CPC     8       // curves per chunk
#define PPL     4       // pixels per lane

// Block = 512 threads = 8 waves; block covers 256 pixels of one batch image.
// Wave w composites curves [8w, 8w+8) for those 256 pixels (4 per lane).
// One LDS curve-record read feeds 4 pixel chains -> DS pipe amortized 4x,
// and 4 independent chains hide VALU latency at 2 waves/SIMD.
__global__ __launch_bounds__(512, 2)
void render_kernel(const float* __restrict__ pos,   // (4, 32, 10)
                   const float* __restrict__ rad,   // (4, 32, 1)
                   const float* __restrict__ col,   // (4, 32, 3)
                   const float* __restrict__ bg,    // (4, 3)
                   float* __restrict__ out)         // (4, 3, 128, 128)
{
    __shared__ float4 s_sub4[NCURVE*NSUB];   // ax, ay, vx, vy
    __shared__ float2 s_sub2[NCURVE*NSUB];   // wx = vx*rvv, wy = vy*rvv
    __shared__ float4 s_cur[NCURVE];         // 1/(r^2*0.05), R, G, B
    __shared__ float4 s_part[NCHUNK*256];    // [chunk][k*64+lane] partial (C, T)

    const int tid  = threadIdx.x;
    const int b    = blockIdx.x >> 6;        // 64 tile-blocks per batch
    const int tile = blockIdx.x & 63;        // 256-pixel tile

    // ---- cooperative setup: 576 sub-segments for this batch ----
    for (int e = tid; e < NCURVE*NSUB; e += 512) {
        const int n    = e / NSUB;
        const int j    = e - n*NSUB;
        const int line = n >> 1;
        const int seg  = n & 1;
        const float* P = pos + (b*NLINES + line)*10;
        float c0x, c0y, c1x, c1y, c2x, c2y;
        if (seg == 0) {                      // p0, p1, p2
            c0x = P[0]; c0y = P[1];
            c1x = P[2]; c1y = P[3];
            c2x = P[4]; c2y = P[5];
        } else {                             // p2, 2*p2 - p3, p4
            const float q2x = P[4], q2y = P[5];
            const float q3x = P[6], q3y = P[7];
            c0x = q2x;             c0y = q2y;
            c1x = 2.0f*q2x - q3x;  c1y = 2.0f*q2y - q3y;
            c2x = P[8];            c2y = P[9];
        }
        const float t0 = (float)j     * (1.0f/9.0f);
        const float t1 = (float)(j+1) * (1.0f/9.0f);
        float ax, ay, bx, by;
        {
            const float mt = 1.0f - t0;
            const float w0 = mt*mt, w1 = 2.0f*t0*mt, w2 = t0*t0;
            ax = w0*c0x + w1*c1x + w2*c2x;
            ay = w0*c0y + w1*c1y + w2*c2y;
        }
        {
            const float mt = 1.0f - t1;
            const float w0 = mt*mt, w1 = 2.0f*t1*mt, w2 = t1*t1;
            bx = w0*c0x + w1*c1x + w2*c2x;
            by = w0*c0y + w1*c1y + w2*c2y;
        }
        const float vx = bx - ax, vy = by - ay;
        const float rvv = 1.0f / (vx*vx + vy*vy + 1e-10f);
        s_sub4[e] = make_float4(ax, ay, vx, vy);
        s_sub2[e] = make_float2(vx*rvv, vy*rvv);
    }
    if (tid < NCURVE) {
        const int line = tid >> 1;
        const float r  = rad[b*NLINES + line];
        s_cur[tid] = make_float4(1.0f / (r*r*0.05f),
                                 col[(b*NLINES + line)*3 + 0],
                                 col[(b*NLINES + line)*3 + 1],
                                 col[(b*NLINES + line)*3 + 2]);
    }
    __syncthreads();

    // ---- hot loop: 8 curves per wave, 4 pixels per lane ----
    const int lane  = tid & 63;
    const int chunk = tid >> 6;              // wave id, wave-uniform

    float g0[PPL], g1[PPL];
    float aR[PPL], aG[PPL], aB[PPL], T[PPL];
    #pragma unroll
    for (int k = 0; k < PPL; ++k) {
        const int p = tile*256 + k*64 + lane;
        g0[k] = -1.0f + (float)(p >> 7)  * (2.0f/127.0f);
        g1[k] = -1.0f + (float)(p & 127) * (2.0f/127.0f);
        aR[k] = 0.0f; aG[k] = 0.0f; aB[k] = 0.0f; T[k] = 1.0f;
    }

    for (int i = 0; i < CPC; ++i) {
        const int n = chunk*CPC + i;
        float edt2[PPL];
        #pragma unroll
        for (int k = 0; k < PPL; ++k) edt2[k] = 3.4e38f;
        #pragma unroll 3
        for (int j = 0; j < NSUB; ++j) {
            const float4 s = s_sub4[n*NSUB + j];
            const float2 w = s_sub2[n*NSUB + j];
            #pragma unroll
            for (int k = 0; k < PPL; ++k) {
                const float d0 = g0[k] - s.x;
                const float d1 = g1[k] - s.y;
                const float tp = fminf(fmaxf(d0*w.x + d1*w.y, 0.0f), 1.0f);
                const float e0 = fmaf(-tp, s.z, d0);
                const float e1 = fmaf(-tp, s.w, d1);
                edt2[k] = fminf(edt2[k], fmaf(e0, e0, e1*e1));
            }
        }
        const float4 cu = s_cur[n];
        #pragma unroll
        for (int k = 0; k < PPL; ++k) {
            const float xs = edt2[k] * cu.x;
            const float I  = __expf(-xs*xs);    // exp(-(edt2/sigma)^2)
            const float wI = I * T[k];
            aR[k] = fmaf(cu.y, wI, aR[k]);
            aG[k] = fmaf(cu.z, wI, aG[k]);
            aB[k] = fmaf(cu.w, wI, aB[k]);
            T[k] *= (1.0f - I + 1e-10f);        // transmittance chain
        }
    }
    #pragma unroll
    for (int k = 0; k < PPL; ++k)
        s_part[chunk*256 + k*64 + lane] = make_float4(aR[k], aG[k], aB[k], T[k]);
    __syncthreads();

    // ---- merge the 8 chunk-partials per pixel, in curve order ----
    if (tid < 256) {
        float4 acc = s_part[tid];
        float C0 = acc.x, C1 = acc.y, C2 = acc.z, Tt = acc.w;
        #pragma unroll
        for (int c = 1; c < NCHUNK; ++c) {
            const float4 q = s_part[c*256 + tid];
            C0 = fmaf(Tt, q.x, C0);
            C1 = fmaf(Tt, q.y, C1);
            C2 = fmaf(Tt, q.z, C2);
            Tt *= q.w;
        }
        C0 = fmaf(Tt, bg[b*3+0], C0);
        C1 = fmaf(Tt, bg[b*3+1], C1);
        C2 = fmaf(Tt, bg[b*3+2], C2);
        const int po = tile*256 + tid;
        out[(b*3+0)*PIX + po] = fminf(fmaxf(C0, 0.0f), 1.0f);
        out[(b*3+1)*PIX + po] = fminf(fmaxf(C1, 0.0f), 1.0f);
        out[(b*3+2)*PIX + po] = fminf(fmaxf(C2, 0.0f), 1.0f);
    }
}

extern "C" void kernel_launch(void* const* d_in, const int* in_sizes, int n_in,
                              void* d_out, int out_size, void* d_ws, size_t ws_size,
                              hipStream_t stream) {
    const float* pos = (const float*)d_in[0];
    const float* rad = (const float*)d_in[1];
    const float* col = (const float*)d_in[2];
    const float* bg  = (const float*)d_in[3];
    float* out = (float*)d_out;

    // 4 batches * 64 tiles of 256 pixels; 8 curve-chunk waves per block
    render_kernel<<<dim3(BS*64), dim3(512), 0, stream>>>(pos, rad, col, bg, out);
}